// Round 1
// 97.182 us; speedup vs baseline: 1.0055x; 1.0055x over previous
//
#include <hip/hip_runtime.h>

// SparseAttention: B=4, M=4096, N=4096, D=128, W=128, fp32 in/out.
// Round 17: R16 screen/ballot kept bit-identical. Post-ballot half
// restructured to be register-resident on the fast path (n<=16):
//  - V pre-converted to fp16 (cvt kernel now emits kh, ki8, vh):
//    V gathers 8->4 VMEM/lane, 128->64 MB L2 traffic, per-batch L2 set
//    2.5 MB (ki8 0.5 + kh 1 + vh 1).
//  - Rescore partials reduced via shfl_xor(1,2,4,8) butterfly (chunk axis
//    = low 4 lane bits); softmax over 16 slots via shfl_xor(16,32) only
//    (slots ≡ r4 mod 4 per lane group, replicated in-group). Weights end
//    up in exactly the lanes that hold the matching V fragments -> no
//    LDS, no barriers, no j<16 serial section on the common path.
//  - LDS-softmax fallback retained for the rare n>16 rows.
// NO VGPR cap (R12 spill lesson), NO screen load batching changes (R11).

typedef __attribute__((ext_vector_type(2))) _Float16 half2v;
typedef __attribute__((ext_vector_type(8))) _Float16 half8;

constexpr int Bc = 4, Mc = 4096, Nc = 4096, Dc = 128, Wc = 128;
constexpr size_t KV_ELEMS = (size_t)Bc * Nc * Dc;   // 2,097,152 per tensor
constexpr float EPS_SCREEN = 3e-6f;
constexpr float QS = 127.f / 6.f;            // int8 scale (|x|<6 covers N(0,1))
constexpr float INV_S = 1.f / (QS * QS);

// ---- pre-pass: K fp32 -> fp16 + packed int8;  V fp32 -> fp16 ----
__global__ __launch_bounds__(256) void cvt_kernel(
    const float* __restrict__ k3d, const float* __restrict__ v3d,
    _Float16* __restrict__ kh, unsigned int* __restrict__ ki8,
    _Float16* __restrict__ vh)
{
    const size_t i = ((size_t)blockIdx.x * blockDim.x + threadIdx.x) * 8;
    if (i >= KV_ELEMS) return;
    const float4 ka = *reinterpret_cast<const float4*>(k3d + i);
    const float4 kb = *reinterpret_cast<const float4*>(k3d + i + 4);
    half8 hk;
    hk[0]=(_Float16)ka.x; hk[1]=(_Float16)ka.y; hk[2]=(_Float16)ka.z; hk[3]=(_Float16)ka.w;
    hk[4]=(_Float16)kb.x; hk[5]=(_Float16)kb.y; hk[6]=(_Float16)kb.z; hk[7]=(_Float16)kb.w;
    *reinterpret_cast<half8*>(kh + i) = hk;
    float f[8] = {ka.x, ka.y, ka.z, ka.w, kb.x, kb.y, kb.z, kb.w};
    unsigned int w0 = 0, w1 = 0;
    #pragma unroll
    for (int jj = 0; jj < 4; ++jj) {
        int v = __float2int_rn(f[jj] * QS);
        v = max(-127, min(127, v));
        w0 |= ((unsigned int)(v & 0xFF)) << (8 * jj);
    }
    #pragma unroll
    for (int jj = 0; jj < 4; ++jj) {
        int v = __float2int_rn(f[4 + jj] * QS);
        v = max(-127, min(127, v));
        w1 |= ((unsigned int)(v & 0xFF)) << (8 * jj);
    }
    *reinterpret_cast<uint2*>(ki8 + i / 4) = make_uint2(w0, w1);

    const float4 va = *reinterpret_cast<const float4*>(v3d + i);
    const float4 vb = *reinterpret_cast<const float4*>(v3d + i + 4);
    half8 hv;
    hv[0]=(_Float16)va.x; hv[1]=(_Float16)va.y; hv[2]=(_Float16)va.z; hv[3]=(_Float16)va.w;
    hv[4]=(_Float16)vb.x; hv[5]=(_Float16)vb.y; hv[6]=(_Float16)vb.z; hv[7]=(_Float16)vb.w;
    *reinterpret_cast<half8*>(vh + i) = hv;
}

__device__ __forceinline__ float dot8_f16(const half8& qv, const half8& kv) {
    const half2v q0 = {qv[0], qv[1]}, q1 = {qv[2], qv[3]},
                 q2 = {qv[4], qv[5]}, q3 = {qv[6], qv[7]};
    const half2v k0 = {kv[0], kv[1]}, k1 = {kv[2], kv[3]},
                 k2 = {kv[4], kv[5]}, k3 = {kv[6], kv[7]};
    float p = __builtin_amdgcn_fdot2(q0, k0, 0.f, false);
    p = __builtin_amdgcn_fdot2(q1, k1, p, false);
    p = __builtin_amdgcn_fdot2(q2, k2, p, false);
    p = __builtin_amdgcn_fdot2(q3, k3, p, false);
    return p;
}

__global__ __launch_bounds__(128) void sparse_attn_r17(
    const float*        __restrict__ q3d,
    const _Float16*     __restrict__ kh,
    const unsigned int* __restrict__ ki8,
    const _Float16*     __restrict__ vh,
    const int*          __restrict__ cidx,
    float*              __restrict__ out)
{
    // 2 independent waves per block, one m-row each; XCD-pinned batches.
    const int blk = blockIdx.x;               // 0..8191
    const int u   = threadIdx.x >> 6;         // wave 0/1
    const int j   = threadIdx.x & 63;         // lane
    const int xcd = blk & 7;
    const int b   = xcd >> 1;
    const int m   = ((blk >> 3) << 2) | ((xcd & 1) << 1) | u;

    __shared__ __align__(16) _Float16 qsh[2][Dc];
    __shared__ __align__(16) unsigned int qpk[2][Dc / 4];
    __shared__ int   cs[2][Wc];
    __shared__ float part[2][8][132];     // screen partials (exact ints as float)
    __shared__ int   widx[2][Wc];
    __shared__ float lswp[2][Wc];         // fallback (n>16) logits/weights only

    {
        const size_t qb = ((size_t)b * Mc + m) * Dc;
        const float qf0 = q3d[qb + j];
        const float qf1 = q3d[qb + 64 + j];
        qsh[u][j]      = (_Float16)qf0;
        qsh[u][64 + j] = (_Float16)qf1;
        int v0 = __float2int_rn(qf0 * QS); v0 = max(-127, min(127, v0));
        int v1 = __float2int_rn(qf1 * QS); v1 = max(-127, min(127, v1));
        reinterpret_cast<signed char*>(qpk[u])[j]      = (signed char)v0;
        reinterpret_cast<signed char*>(qpk[u])[64 + j] = (signed char)v1;
        cs[u][j]      = cidx[m * Wc + j];
        cs[u][64 + j] = cidx[m * Wc + 64 + j];
        widx[u][j] = 0; widx[u][64 + j] = 0;   // empty slots -> row 0
    }
    __builtin_amdgcn_wave_barrier();

    // ---- Screen: int8 rows (128 B), 8 rows per instr, 16 hoisted gathers ----
    const int c8 = j & 7;     // 16-B chunk (elems c8*16..+16)
    const int r8 = j >> 3;    // row-in-volley 0..7
    const uint4* kbq = reinterpret_cast<const uint4*>(ki8 + (size_t)b * Nc * Dc / 4);
    const int qd0 = (int)qpk[u][c8 * 4 + 0], qd1 = (int)qpk[u][c8 * 4 + 1],
              qd2 = (int)qpk[u][c8 * 4 + 2], qd3 = (int)qpk[u][c8 * 4 + 3];

    int rb[16];
    #pragma unroll
    for (int i = 0; i < 16; ++i) rb[i] = cs[u][i * 8 + r8] * 8 + c8;  // uint4 units
    uint4 kr[16];
    #pragma unroll
    for (int i = 0; i < 16; ++i) kr[i] = kbq[rb[i]];
    #pragma unroll
    for (int i = 0; i < 16; ++i) {
        int d = __builtin_amdgcn_sdot4(qd0, (int)kr[i].x, 0, false);
        d = __builtin_amdgcn_sdot4(qd1, (int)kr[i].y, d, false);
        d = __builtin_amdgcn_sdot4(qd2, (int)kr[i].z, d, false);
        d = __builtin_amdgcn_sdot4(qd3, (int)kr[i].w, d, false);
        part[u][c8][i * 8 + r8] = (float)d;   // |d| < 2^24: exact in fp32
    }
    __builtin_amdgcn_wave_barrier();

    float Lf0 = 0.f, Lf1 = 0.f;               // sums < 2^24: exact
    #pragma unroll
    for (int c = 0; c < 8; ++c) { Lf0 += part[u][c][j]; Lf1 += part[u][c][64 + j]; }
    const float L0 = Lf0 * INV_S;
    const float L1 = Lf1 * INV_S;

    // ---- Screening softmax (intra-wave, 2 logits/lane) ----
    float mx = fmaxf(L0, L1);
    #pragma unroll
    for (int o = 32; o; o >>= 1) mx = fmaxf(mx, __shfl_xor(mx, o));
    const float e0 = __expf(L0 - mx), e1 = __expf(L1 - mx);
    float ssum = e0 + e1;
    #pragma unroll
    for (int o = 32; o; o >>= 1) ssum += __shfl_xor(ssum, o);
    const float inv_ssum = 1.f / ssum;

    // ---- Ballot compaction (no atomics) ----
    const unsigned long long mk0 = __ballot(e0 * inv_ssum >= EPS_SCREEN);
    const unsigned long long mk1 = __ballot(e1 * inv_ssum >= EPS_SCREEN);
    const int n0 = __popcll(mk0);
    const int n  = n0 + __popcll(mk1);
    const unsigned long long lt = (j == 0) ? 0ull : (~0ull >> (64 - j));
    if (mk0 & (1ull << j)) widx[u][__popcll(mk0 & lt)]      = cs[u][j];
    if (mk1 & (1ull << j)) widx[u][n0 + __popcll(mk1 & lt)] = cs[u][64 + j];
    __builtin_amdgcn_wave_barrier();

    // ---- Volley 2: fp16 K rescore + fp16 V, same (slot,chunk) lane map ----
    // lane j: chunk c16 = j&15 (d = c16*8..+7), slot group r4 = j>>4;
    // this lane touches slots r4, r4+4, r4+8, r4+12 for BOTH K and V.
    const int c16 = j & 15;
    const int r4  = j >> 4;
    const half8* kb16 = reinterpret_cast<const half8*>(kh + (size_t)b * Nc * Dc);
    const half8* vb16 = reinterpret_cast<const half8*>(vh + (size_t)b * Nc * Dc);
    const half8 qv = *reinterpret_cast<const half8*>(&qsh[u][c16 * 8]);

    int rowi[4];
    #pragma unroll
    for (int t = 0; t < 4; ++t) rowi[t] = widx[u][t * 4 + r4] * 16 + c16;

    half8 kk[4], vv[4];
    #pragma unroll
    for (int t = 0; t < 4; ++t)
        kk[t] = (t * 4 + r4 < n) ? kb16[rowi[t]] : half8{};
    #pragma unroll
    for (int t = 0; t < 4; ++t)   // widx pre-zeroed: empty slots read row 0
        vv[t] = (t * 4 + r4 < n) ? vb16[rowi[t]] : half8{};

    float L[4];
    #pragma unroll
    for (int t = 0; t < 4; ++t) L[t] = dot8_f16(qv, kk[t]);
    // butterfly over chunk axis (low 4 lane bits): full logits, replicated
    // across the 16 lanes of each r4 group.
    #pragma unroll
    for (int o = 1; o <= 8; o <<= 1) {
        #pragma unroll
        for (int t = 0; t < 4; ++t) L[t] += __shfl_xor(L[t], o);
    }

    float w[4];
    if (n <= 16) {
        // ---- register softmax: groups own disjoint slot sets -> two hops ----
        float mx2 = -1e30f;
        #pragma unroll
        for (int t = 0; t < 4; ++t) {
            L[t] = (t * 4 + r4 < n) ? L[t] : -1e30f;
            mx2 = fmaxf(mx2, L[t]);
        }
        mx2 = fmaxf(mx2, __shfl_xor(mx2, 16));
        mx2 = fmaxf(mx2, __shfl_xor(mx2, 32));
        float s2 = 0.f;
        #pragma unroll
        for (int t = 0; t < 4; ++t) {
            w[t] = (t * 4 + r4 < n) ? __expf(L[t] - mx2) : 0.f;
            s2 += w[t];
        }
        s2 += __shfl_xor(s2, 16);     // each slot counted exactly once
        s2 += __shfl_xor(s2, 32);
        const float i2 = 1.f / s2;
        #pragma unroll
        for (int t = 0; t < 4; ++t) w[t] *= i2;
    } else {
        // ---- rare fallback: materialize logits in LDS, exact softmax ----
        if (c16 == 0) {
            #pragma unroll
            for (int t = 0; t < 4; ++t) lswp[u][t * 4 + r4] = L[t];
        }
        for (int base = 16; base < n; base += 16) {
            float L2v[4];
            #pragma unroll
            for (int t = 0; t < 4; ++t) {
                const int slot = base + t * 4 + r4;            // <= 127
                half8 kx = (slot < n) ? kb16[widx[u][slot] * 16 + c16] : half8{};
                L2v[t] = dot8_f16(qv, kx);
            }
            #pragma unroll
            for (int o = 1; o <= 8; o <<= 1) {
                #pragma unroll
                for (int t = 0; t < 4; ++t) L2v[t] += __shfl_xor(L2v[t], o);
            }
            if (c16 == 0) {
                #pragma unroll
                for (int t = 0; t < 4; ++t)
                    if (base + t * 4 + r4 < n) lswp[u][base + t * 4 + r4] = L2v[t];
            }
        }
        __builtin_amdgcn_wave_barrier();
        const float A  = (j < n)      ? lswp[u][j]      : -1e30f;
        const float B2 = (64 + j < n) ? lswp[u][64 + j] : -1e30f;
        float mx2 = fmaxf(A, B2);
        #pragma unroll
        for (int o = 32; o; o >>= 1) mx2 = fmaxf(mx2, __shfl_xor(mx2, o));
        const float ea = (j < n)      ? __expf(A - mx2)  : 0.f;
        const float eb = (64 + j < n) ? __expf(B2 - mx2) : 0.f;
        float s2 = ea + eb;
        #pragma unroll
        for (int o = 32; o; o >>= 1) s2 += __shfl_xor(s2, o);
        const float i2 = 1.f / s2;
        lswp[u][j]      = (j < n)      ? ea * i2 : 0.f;
        lswp[u][64 + j] = (64 + j < n) ? eb * i2 : 0.f;
        __builtin_amdgcn_wave_barrier();
        #pragma unroll
        for (int t = 0; t < 4; ++t) w[t] = lswp[u][t * 4 + r4];
    }

    // ---- Apply weights to the fp16 V fragments already in registers ----
    float acc[8];
    #pragma unroll
    for (int e = 0; e < 8; ++e) acc[e] = 0.f;
    #pragma unroll
    for (int t = 0; t < 4; ++t) {
        #pragma unroll
        for (int e = 0; e < 8; ++e) acc[e] += w[t] * (float)vv[t][e];
    }
    if (n > 16) {                                   // rare fallback slots
        for (int s = 16 + r4; s < n; s += 4) {
            const half8 vx = vb16[widx[u][s] * 16 + c16];
            const float ws2 = lswp[u][s];
            #pragma unroll
            for (int e = 0; e < 8; ++e) acc[e] += ws2 * (float)vx[e];
        }
    }
    // reduce across the 4 slot groups (same chunk c16 lives at j^16/j^32/j^48)
    #pragma unroll
    for (int e = 0; e < 8; ++e) {
        acc[e] += __shfl_xor(acc[e], 16);
        acc[e] += __shfl_xor(acc[e], 32);
    }
    if (j < 32) {   // lanes 0..15 -> even float4s, 16..31 -> odd float4s
        float4 o4;
        o4.x = r4 ? acc[4] : acc[0];
        o4.y = r4 ? acc[5] : acc[1];
        o4.z = r4 ? acc[6] : acc[2];
        o4.w = r4 ? acc[7] : acc[3];
        reinterpret_cast<float4*>(out + ((size_t)b * Mc + m) * Dc)[2 * c16 + r4] = o4;
    }
}

extern "C" void kernel_launch(void* const* d_in, const int* in_sizes, int n_in,
                              void* d_out, int out_size, void* d_ws, size_t ws_size,
                              hipStream_t stream) {
    const float* q = (const float*)d_in[0];
    const float* k = (const float*)d_in[1];
    const float* v = (const float*)d_in[2];
    const int*   c = (const int*)d_in[3];
    float*       o = (float*)d_out;
    (void)in_sizes; (void)n_in; (void)out_size; (void)ws_size;

    _Float16*     kh  = (_Float16*)d_ws;                                        // 4 MB
    unsigned int* ki8 = (unsigned int*)((char*)d_ws + KV_ELEMS * sizeof(_Float16)); // 2 MB
    _Float16*     vh  = (_Float16*)((char*)d_ws + KV_ELEMS * sizeof(_Float16)
                                                 + KV_ELEMS * sizeof(char));    // 4 MB

    const int cvt_threads = 256;
    const int cvt_blocks  = (int)(KV_ELEMS / 8 / cvt_threads);   // 1024
    cvt_kernel<<<cvt_blocks, cvt_threads, 0, stream>>>(k, v, kh, ki8, vh);

    sparse_attn_r17<<<dim3(Bc * Mc / 2), dim3(128), 0, stream>>>(q, kh, ki8, vh, c, o);
}